// Round 1
// baseline (2951.647 us; speedup 1.0000x reference)
//
#include <hip/hip_runtime.h>
#include <hip/hip_bf16.h>
#include <stdint.h>

#define T_TOK 4096
#define DIN   4096
#define DOUT  4096
#define NE    8

typedef __attribute__((ext_vector_type(8))) short short8;
typedef __attribute__((ext_vector_type(4))) float floatx4;

// ---- ws layout (bytes) ----
// [0, 33554432)            x_bf16 (uint16_t, T*DIN)
// [33554432, +131072)      perm   (int,   NE*T)
// [33685504, +131072)      pscore (float, NE*T)
// [33816576, +32)          counts (int NE)
// [33816608, +32)          importance (float NE)
static const size_t OFF_XBF    = 0;
static const size_t OFF_PERM   = (size_t)T_TOK * DIN * 2;
static const size_t OFF_PSCORE = OFF_PERM + (size_t)4 * NE * T_TOK;
static const size_t OFF_COUNTS = OFF_PSCORE + (size_t)4 * NE * T_TOK;
static const size_t OFF_IMP    = OFF_COUNTS + 32;

__device__ inline uint32_t pk_bf16(float a, float b) {
    __hip_bfloat162 h = __float22bfloat162_rn(make_float2(a, b));
    union { __hip_bfloat162 h; uint32_t u; } cv;
    cv.h = h;
    return cv.u;
}

// ---------------- x fp32 -> bf16 ----------------
__global__ __launch_bounds__(256) void cast_x_kernel(const float* __restrict__ x,
                                                     uint16_t* __restrict__ xb) {
    int i = (blockIdx.x * 256 + threadIdx.x) * 4;
    float4 v = *reinterpret_cast<const float4*>(x + i);
    uint2 p;
    p.x = pk_bf16(v.x, v.y);
    p.y = pk_bf16(v.z, v.w);
    *reinterpret_cast<uint2*>(xb + i) = p;
}

// ---------------- gate + routing ----------------
__global__ __launch_bounds__(256) void gate_kernel(
    const float* __restrict__ x, const float* __restrict__ w1,
    const float* __restrict__ w2, int* __restrict__ perm,
    float* __restrict__ pscore, int* __restrict__ counts,
    float* __restrict__ importance)
{
    int t = blockIdx.x;
    int tid = threadIdx.x;
    int g = tid >> 5;      // expert group 0..7
    int l = tid & 31;
    const float* xr = x + (size_t)t * DIN;
    const float* wr = w1 + (size_t)g * DIN;
    float sum = 0.f;
    for (int i = l * 4; i < DIN; i += 128) {
        float4 xv = *reinterpret_cast<const float4*>(xr + i);
        float4 wv = *reinterpret_cast<const float4*>(wr + i);
        sum += xv.x * wv.x + xv.y * wv.y + xv.z * wv.z + xv.w * wv.w;
    }
#pragma unroll
    for (int off = 16; off; off >>= 1) sum += __shfl_xor(sum, off, 64);

    __shared__ float sh[NE];
    __shared__ float lg[NE];
    if (l == 0) sh[g] = tanhf(sum);
    __syncthreads();
    if (tid < NE) {
        float acc = 0.f;
#pragma unroll
        for (int e2 = 0; e2 < NE; ++e2) acc += sh[e2] * w2[tid * NE + e2];
        lg[tid] = acc;
    }
    __syncthreads();
    if (tid == 0) {
        // top-2 (strict > keeps lowest index on ties, matching lax.top_k)
        int i1 = 0; float l1 = lg[0];
        for (int e2 = 1; e2 < NE; ++e2)
            if (lg[e2] > l1) { l1 = lg[e2]; i1 = e2; }
        int i2 = -1; float l2 = -1e30f;
        for (int e2 = 0; e2 < NE; ++e2)
            if (e2 != i1 && lg[e2] > l2) { l2 = lg[e2]; i2 = e2; }
        float ee = expf(l2 - l1);
        float p1 = 1.f / (1.f + ee);
        float p2 = ee / (1.f + ee);
        int pos1 = atomicAdd(&counts[i1], 1);
        perm[i1 * T_TOK + pos1] = t;
        pscore[i1 * T_TOK + pos1] = p1;
        int pos2 = atomicAdd(&counts[i2], 1);
        perm[i2 * T_TOK + pos2] = t;
        pscore[i2 * T_TOK + pos2] = p2;
        atomicAdd(&importance[i1], p1);
        atomicAdd(&importance[i2], p2);
    }
}

// ---------------- expert GEMM (gathered A, scattered C) ----------------
// 128x128 tile, BK=32, 4 waves of 4x4 16x16x32 bf16 MFMA.
__global__ __launch_bounds__(256) void moe_gemm_kernel(
    const uint16_t* __restrict__ xb, const float* __restrict__ ew,
    const float* __restrict__ eb, const int* __restrict__ perm,
    const float* __restrict__ pscore, const int* __restrict__ counts,
    float* __restrict__ out)
{
    const int e = blockIdx.z;
    const int ne = counts[e];
    const int m0 = blockIdx.x * 128;   // m fastest-varying: W-strip sharers dispatch together
    if (m0 >= ne) return;
    const int n0 = blockIdx.y * 128;
    const int tid = threadIdx.x;

    __shared__ int   s_tok[128];
    __shared__ float s_sc[128];
    __shared__ __align__(16) uint16_t As[128 * 40];  // pad 32->40: 80B stride, 16B-aligned
    __shared__ __align__(16) uint16_t Bs[128 * 40];

    if (tid < 128) {
        int idx = m0 + tid;
        if (idx < ne) {
            s_tok[tid] = perm[e * T_TOK + idx];
            s_sc[tid]  = pscore[e * T_TOK + idx];
        } else {
            s_tok[tid] = -1;
            s_sc[tid]  = 0.f;
        }
    }
    __syncthreads();

    const int row  = tid >> 1;
    const int half = tid & 1;
    const int tokr = s_tok[row];
    const uint16_t* asrc = xb + (size_t)(tokr < 0 ? 0 : tokr) * DIN + half * 16;
    const float*    bsrc = ew + (size_t)e * DOUT * DIN + (size_t)(n0 + row) * DIN + half * 16;
    uint16_t* adst = &As[row * 40 + half * 16];
    uint16_t* bdst = &Bs[row * 40 + half * 16];

    const int lane = tid & 63;
    const int wid  = tid >> 6;
    const int wm   = (wid >> 1) * 64;
    const int wn   = (wid & 1) * 64;
    const int quad = lane >> 4;
    const int mr   = lane & 15;

    floatx4 acc[4][4] = {};

    for (int kk = 0; kk < DIN; kk += 32) {
        // stage A (bf16 passthrough)
        uint4 a0 = *reinterpret_cast<const uint4*>(asrc + kk);
        uint4 a1 = *reinterpret_cast<const uint4*>(asrc + kk + 8);
        // stage B (fp32 -> bf16 on the fly)
        float4 f0 = *reinterpret_cast<const float4*>(bsrc + kk);
        float4 f1 = *reinterpret_cast<const float4*>(bsrc + kk + 4);
        float4 f2 = *reinterpret_cast<const float4*>(bsrc + kk + 8);
        float4 f3 = *reinterpret_cast<const float4*>(bsrc + kk + 12);
        uint4 b0, b1;
        b0.x = pk_bf16(f0.x, f0.y); b0.y = pk_bf16(f0.z, f0.w);
        b0.z = pk_bf16(f1.x, f1.y); b0.w = pk_bf16(f1.z, f1.w);
        b1.x = pk_bf16(f2.x, f2.y); b1.y = pk_bf16(f2.z, f2.w);
        b1.z = pk_bf16(f3.x, f3.y); b1.w = pk_bf16(f3.z, f3.w);
        *reinterpret_cast<uint4*>(adst)     = a0;
        *reinterpret_cast<uint4*>(adst + 8) = a1;
        *reinterpret_cast<uint4*>(bdst)     = b0;
        *reinterpret_cast<uint4*>(bdst + 8) = b1;
        __syncthreads();

        short8 af[4], bf[4];
#pragma unroll
        for (int i = 0; i < 4; ++i)
            af[i] = *reinterpret_cast<const short8*>(&As[(wm + i * 16 + mr) * 40 + quad * 8]);
#pragma unroll
        for (int j = 0; j < 4; ++j)
            bf[j] = *reinterpret_cast<const short8*>(&Bs[(wn + j * 16 + mr) * 40 + quad * 8]);
#pragma unroll
        for (int i = 0; i < 4; ++i)
#pragma unroll
            for (int j = 0; j < 4; ++j)
                acc[i][j] = __builtin_amdgcn_mfma_f32_16x16x32_bf16(af[i], bf[j], acc[i][j], 0, 0, 0);
        __syncthreads();
    }

    // epilogue: out[tok, col] += score * (acc + bias)
    const float* brow = eb + (size_t)e * DOUT + n0 + wn;
    float bj[4];
#pragma unroll
    for (int j = 0; j < 4; ++j) bj[j] = brow[j * 16 + mr];
#pragma unroll
    for (int i = 0; i < 4; ++i) {
#pragma unroll
        for (int r = 0; r < 4; ++r) {
            int idx = wm + i * 16 + quad * 4 + r;
            int tok = s_tok[idx];
            if (tok < 0) continue;
            float sc = s_sc[idx];
            float* orow = out + (size_t)tok * DOUT + n0 + wn;
#pragma unroll
            for (int j = 0; j < 4; ++j)
                atomicAdd(&orow[j * 16 + mr], sc * (acc[i][j][r] + bj[j]));
        }
    }
}

// ---------------- balance loss ----------------
__global__ void balance_kernel(const int* __restrict__ counts,
                               const float* __restrict__ importance,
                               float* __restrict__ out_loss) {
    if (threadIdx.x == 0) {
        float mi = 0.f, ml = 0.f;
        for (int e = 0; e < NE; ++e) { mi += importance[e]; ml += (float)counts[e]; }
        mi /= NE; ml /= NE;
        float vi = 0.f, vl = 0.f;
        for (int e = 0; e < NE; ++e) {
            float di = importance[e] - mi; vi += di * di;
            float dl = (float)counts[e] - ml; vl += dl * dl;
        }
        vi /= (NE - 1); vl /= (NE - 1);
        *out_loss = 0.01f * (vi / (mi * mi + 1e-10f) + vl / (ml * ml + 1e-10f));
    }
}

extern "C" void kernel_launch(void* const* d_in, const int* in_sizes, int n_in,
                              void* d_out, int out_size, void* d_ws, size_t ws_size,
                              hipStream_t stream)
{
    const float* x  = (const float*)d_in[0];
    const float* w1 = (const float*)d_in[1];
    const float* w2 = (const float*)d_in[2];
    const float* ew = (const float*)d_in[3];
    const float* eb = (const float*)d_in[4];
    float* out = (float*)d_out;

    char* ws = (char*)d_ws;
    uint16_t* xb      = (uint16_t*)(ws + OFF_XBF);
    int*      perm    = (int*)(ws + OFF_PERM);
    float*    pscore  = (float*)(ws + OFF_PSCORE);
    int*      counts  = (int*)(ws + OFF_COUNTS);
    float*    imp     = (float*)(ws + OFF_IMP);

    hipMemsetAsync(ws + OFF_COUNTS, 0, 64, stream);
    hipMemsetAsync(d_out, 0, (size_t)out_size * sizeof(float), stream);

    cast_x_kernel<<<(T_TOK * DIN) / 1024, 256, 0, stream>>>(x, xb);
    gate_kernel<<<T_TOK, 256, 0, stream>>>(x, w1, w2, perm, pscore, counts, imp);
    moe_gemm_kernel<<<dim3(32, 32, 8), 256, 0, stream>>>(xb, ew, eb, perm, pscore, counts, out);
    balance_kernel<<<1, 64, 0, stream>>>(counts, imp, out + (out_size - 1));
}